// Round 9
// baseline (295.090 us; speedup 1.0000x reference)
//
#include <hip/hip_runtime.h>
#include <math.h>

#define G_MAX 512   // sorted gt slots (padding sorts to end); setup G=300
#define SPLIT 4     // threads per anchor (g-loop split)
#define NBINS 4096  // counting-sort bins over anchor x0 in [-128, 1152)

__device__ __forceinline__ int binOf(float ax0) {
  float t = (ax0 + 128.0f) * ((float)NBINS / 1280.0f);
  int b = (int)t;
  b = b < 0 ? 0 : b;
  return b > NBINS - 1 ? NBINS - 1 : b;
}

// hist + (last block) inline exclusive scan -> cursor
__global__ __launch_bounds__(256) void k_hist_scan(
    const float* __restrict__ anchors, int A, int numBlocks,
    unsigned int* __restrict__ binCnt, unsigned int* __restrict__ cursor,
    unsigned int* __restrict__ tick) {
  __shared__ unsigned int part[256];
  __shared__ int last;
  int i = blockIdx.x * 256 + threadIdx.x;
  if (i < A) atomicAdd(&binCnt[binOf(anchors[i * 4])], 1u);
  __threadfence();
  __syncthreads();
  if (threadIdx.x == 0) {
    unsigned int old = atomicAdd(tick, 1u);
    last = (old == (unsigned int)(numBlocks - 1)) ? 1 : 0;
  }
  __syncthreads();
  if (last) {
    unsigned int v[NBINS / 256];
    unsigned int s = 0;
    int base = threadIdx.x * (NBINS / 256);
#pragma unroll
    for (int k = 0; k < NBINS / 256; ++k) { v[k] = atomicAdd(&binCnt[base + k], 0u); s += v[k]; }
    part[threadIdx.x] = s;
    __syncthreads();
    for (int o = 1; o < 256; o <<= 1) {
      unsigned int t = (threadIdx.x >= (unsigned)o) ? part[threadIdx.x - o] : 0u;
      __syncthreads();
      part[threadIdx.x] += t;
      __syncthreads();
    }
    unsigned int excl = part[threadIdx.x] - s;
#pragma unroll
    for (int k = 0; k < NBINS / 256; ++k) { cursor[base + k] = excl; excl += v[k]; }
  }
}

__global__ __launch_bounds__(256) void k_scatter(const float* __restrict__ anchors, int A,
                                                 unsigned int* __restrict__ cursor,
                                                 int* __restrict__ perm) {
  int i = blockIdx.x * 256 + threadIdx.x;
  if (i < A) {
    unsigned int pos = atomicAdd(&cursor[binOf(anchors[i * 4])], 1u);
    perm[pos] = i;  // within-bin order arbitrary: loss is a permutation-invariant sum
  }
}

// One block per image: O(G^2) rank-sort of VALID gts by (x0, idx); padding after.
__global__ __launch_bounds__(256) void k_sortgt(const float* __restrict__ boxes, int G,
                                                float4* __restrict__ sgt,
                                                float* __restrict__ sga,
                                                float* __restrict__ maxWp) {
  __shared__ float x0s[G_MAX], y0s[G_MAX], x1s[G_MAX], y1s[G_MAX];
  __shared__ unsigned char vld[G_MAX];
  __shared__ float red[256];
  int img = blockIdx.x;
  const float* gtb = boxes + (size_t)img * G * 5;
  float wmax = 0.f;
  for (int g = threadIdx.x; g < G; g += 256) {
    float x0 = gtb[g * 5 + 0], y0 = gtb[g * 5 + 1];
    float x1 = gtb[g * 5 + 2], y1 = gtb[g * 5 + 3];
    float lb = gtb[g * 5 + 4];
    x0s[g] = x0; y0s[g] = y0; x1s[g] = x1; y1s[g] = y1;
    bool v = (lb != -1.0f);
    vld[g] = v ? 1 : 0;
    if (v) wmax = fmaxf(wmax, (x1 + 1.0f) - x0);
  }
  // init all output slots to inert padding (x0=3e38 -> outside any window)
  for (int g = threadIdx.x; g < G_MAX; g += 256) {
    sgt[img * G_MAX + g] = make_float4(3e38f, 0.f, -3e38f, 1.f);
    sga[img * G_MAX + g] = 1e30f;
  }
  red[threadIdx.x] = wmax;
  __syncthreads();  // LDS ready + padding writes ordered before rank writes
  for (int g = threadIdx.x; g < G; g += 256) {
    if (vld[g]) {
      float xg = x0s[g];
      int r = 0;
      for (int j = 0; j < G; ++j)
        r += (vld[j] && (x0s[j] < xg || (x0s[j] == xg && j < g))) ? 1 : 0;
      sgt[img * G_MAX + r] = make_float4(xg, y0s[g], x1s[g] + 1.0f, y1s[g] + 1.0f);
      sga[img * G_MAX + r] = (x1s[g] - x0s[g] + 1.0f) * (y1s[g] - y0s[g] + 1.0f);
    }
  }
  for (int o = 128; o > 0; o >>= 1) {
    __syncthreads();
    if (threadIdx.x < (unsigned)o) red[threadIdx.x] = fmaxf(red[threadIdx.x], red[threadIdx.x + o]);
  }
  __syncthreads();
  if (threadIdx.x == 0) maxWp[img] = red[0];
}

// streaming permute of per-anchor inputs into sorted order (scattered reads,
// coalesced writes; latency-tolerant so the main kernel never pays divergence)
__global__ __launch_bounds__(256) void k_gather(
    const float* __restrict__ anchors, const float* __restrict__ pred_reg,
    const float* __restrict__ pred_cls, const float* __restrict__ rpn_iou,
    const float* __restrict__ rpn_num, const int* __restrict__ perm, int A, int nImg,
    float4* __restrict__ gAnch, float4* __restrict__ gReg,
    float2* __restrict__ gPC, float2* __restrict__ gRI, float2* __restrict__ gSN) {
  int pos = blockIdx.x * 256 + threadIdx.x;
  if (pos >= A) return;
  int ic = perm[pos];
  gAnch[pos] = ((const float4*)anchors)[ic];
  for (int img = 0; img < nImg; ++img) {
    size_t src = (size_t)img * A + ic;
    size_t dst = (size_t)img * A + pos;
    const float4* rr = (const float4*)pred_reg;
    gReg[2 * dst + 0] = rr[2 * src + 0];
    gReg[2 * dst + 1] = rr[2 * src + 1];
    gPC[dst] = ((const float2*)pred_cls)[src];
    gRI[dst] = ((const float2*)rpn_iou)[src];
    gSN[dst] = ((const float2*)rpn_num)[src];
  }
}

__device__ __forceinline__ float waveSum(float v) {
#pragma unroll
  for (int o = 32; o > 0; o >>= 1) v += __shfl_down(v, o, 64);
  return v;
}

__device__ __forceinline__ float huber9(float x) {
  float ax = fabsf(x);
  return (ax < (1.0f / 9.0f)) ? 4.5f * x * x : ax - (0.5f / 9.0f);
}

// Exact IoU in the reference's op order. g = (x0, y0, x1+1, y1+1)
__device__ __forceinline__ float iouExact(float bx0, float by0, float bx1, float by1,
                                          float areab, float4 g, float areag) {
  float gx1 = g.z - 1.0f, gy1 = g.w - 1.0f;
  float iw = fminf(bx1, gx1) - fmaxf(bx0, g.x) + 1.0f;
  float ih = fminf(by1, gy1) - fmaxf(by0, g.y) + 1.0f;
  float inter = fmaxf(iw, 0.f) * fmaxf(ih, 0.f);
  float uni = areab + areag - inter;
  return inter / fmaxf(uni, 1.0f);
}

// R5-R8 proven inverse key: key=(areaB+areaG)*rcp(inter), inter=max(iw,0)*ih
// (one-clamp); argmax iou == argmin key as uint; negative/inf keys form the
// zero-overlap class whose internal order is output-invariant. Low 9 bits
// carry the SORTED gt index; min-ties -> smallest sorted index.
__device__ __forceinline__ uint32_t packKey(float x0, float y0, float x1p, float y1p,
                                            float area, float4 gb, float ga,
                                            uint32_t g) {
  float iw = fminf(x1p, gb.z) - fmaxf(x0, gb.x);
  float ih = fminf(y1p, gb.w) - fmaxf(y0, gb.y);
  float inter = fmaxf(iw, 0.f) * ih;
  float key = (area + ga) * __builtin_amdgcn_rcpf(inter);
  return (__float_as_uint(key) & 0xFFFFFE00u) | g;
}

__global__ __launch_bounds__(256) void retina_main(
    const float* __restrict__ pred_cls, const float* __restrict__ rpn_num,
    const float* __restrict__ pred_reg, const float* __restrict__ anchors,
    const float* __restrict__ rpn_iou,
    const float4* __restrict__ sgt, const float* __restrict__ sga,
    const float* __restrict__ maxWp, const int* __restrict__ perm,
    const float4* __restrict__ gAnch, const float4* __restrict__ gReg,
    const float2* __restrict__ gPC, const float2* __restrict__ gRI,
    const float2* __restrict__ gSN,
    int gathered, int A, int totalBlocks,
    double* __restrict__ acc, unsigned int* __restrict__ cnt,
    float* __restrict__ out) {
  __shared__ float4 sBox[G_MAX];
  __shared__ float sA[G_MAX];
  __shared__ float sRed[4][7];
  __shared__ int sLast;

  const int img = blockIdx.y;
  const int seg = threadIdx.x & (SPLIT - 1);
  const int al = threadIdx.x >> 2;
  const int pos = blockIdx.x * 64 + al;        // position in sorted order
  const int posc = (pos < A) ? pos : (A - 1);

  for (int g = threadIdx.x; g < G_MAX; g += 256) {
    sBox[g] = sgt[img * G_MAX + g];
    sA[g] = sga[img * G_MAX + g];
  }
  __syncthreads();

  float t_cls = 0.f, t_bbox = 0.f, t_iou = 0.f, t_num = 0.f;
  float t_npos = 0.f, t_nfg = 0.f, t_ncnt = 0.f;

  const float BBOX_CLIP = 4.1351666f;  // log(1000/16)

  float ax0, ay0, ax1, ay1, d0, d1, d2, d3, d4, d5, d6, d7;
  float pcv0 = 0.f, pcv1 = 0.f, riv0 = 0.f, riv1 = 0.f, sn0 = 0.f, sn1 = 0.f;

  if (gathered) {
    float4 av = gAnch[posc];
    ax0 = av.x; ay0 = av.y; ax1 = av.z; ay1 = av.w;
    size_t idx = (size_t)img * A + posc;
    float4 r0 = gReg[2 * idx], r1 = gReg[2 * idx + 1];
    d0 = r0.x; d1 = r0.y; d2 = r0.z; d3 = r0.w;
    d4 = r1.x; d5 = r1.y; d6 = r1.z; d7 = r1.w;
    if (seg == 0) {
      float2 a = gPC[idx]; pcv0 = a.x; pcv1 = a.y;
      float2 b = gRI[idx]; riv0 = b.x; riv1 = b.y;
      float2 c = gSN[idx]; sn0 = c.x; sn1 = c.y;
    }
  } else {
    int ic = perm[posc];
    float4 av = ((const float4*)anchors)[ic];
    ax0 = av.x; ay0 = av.y; ax1 = av.z; ay1 = av.w;
    size_t idx = (size_t)img * A + ic;
    const float4* rr = (const float4*)pred_reg;
    float4 r0 = rr[2 * idx], r1 = rr[2 * idx + 1];
    d0 = r0.x; d1 = r0.y; d2 = r0.z; d3 = r0.w;
    d4 = r1.x; d5 = r1.y; d6 = r1.z; d7 = r1.w;
    if (seg == 0) {
      float2 a = ((const float2*)pred_cls)[idx]; pcv0 = a.x; pcv1 = a.y;
      float2 b = ((const float2*)rpn_iou)[idx];  riv0 = b.x; riv1 = b.y;
      float2 c = ((const float2*)rpn_num)[idx];  sn0 = c.x; sn1 = c.y;
    }
  }

  float aw = ax1 - ax0 + 1.0f, ah = ay1 - ay0 + 1.0f;
  float areaa = aw * ah;
  float acx = ax0 + 0.5f * aw, acy = ay0 + 0.5f * ah;
  float ax1p = ax1 + 1.0f, ay1p = ay1 + 1.0f;

  float p0cx = acx + d0 * aw, p0cy = acy + d1 * ah;
  float p0w = aw * expf(fminf(d2, BBOX_CLIP));
  float p0h = ah * expf(fminf(d3, BBOX_CLIP));
  float b0x0 = p0cx - 0.5f * p0w, b0y0 = p0cy - 0.5f * p0h;
  float b0x1 = p0cx + 0.5f * p0w, b0y1 = p0cy + 0.5f * p0h;
  float area0 = (b0x1 - b0x0 + 1.0f) * (b0y1 - b0y0 + 1.0f);
  float b0x1p = b0x1 + 1.0f, b0y1p = b0y1 + 1.0f;

  float p1cx = acx + d4 * aw, p1cy = acy + d5 * ah;
  float p1w = aw * expf(fminf(d6, BBOX_CLIP));
  float p1h = ah * expf(fminf(d7, BBOX_CLIP));
  float b1x0 = p1cx - 0.5f * p1w, b1y0 = p1cy - 0.5f * p1h;
  float b1x1 = p1cx + 0.5f * p1w, b1y1 = p1cy + 0.5f * p1h;
  float area1 = (b1x1 - b1x0 + 1.0f) * (b1y1 - b1y0 + 1.0f);
  float b1x1p = b1x1 + 1.0f, b1y1p = b1y1 + 1.0f;

  // per-wave x-window: gts outside have inter<=0 for every box in the wave
  float bxlo = fminf(ax0, fminf(b0x0, b1x0));
  float bxhi = fmaxf(ax1p, fmaxf(b0x1p, b1x1p));
#pragma unroll
  for (int o = 32; o > 0; o >>= 1) {
    bxlo = fminf(bxlo, __shfl_xor(bxlo, o, 64));
    bxhi = fmaxf(bxhi, __shfl_xor(bxhi, o, 64));
  }
  float loB = bxlo - maxWp[img];
  int s, e;
  { int lo = 0, hi = G_MAX;
    while (lo < hi) { int m = (lo + hi) >> 1; if (sBox[m].x < loB) lo = m + 1; else hi = m; }
    s = lo; }
  { int lo = 0, hi = G_MAX;
    while (lo < hi) { int m = (lo + hi) >> 1; if (sBox[m].x < bxhi) lo = m + 1; else hi = m; }
    e = lo; }

  uint32_t an1 = 0xFFFFFFFFu, an2 = 0xFFFFFFFFu;
  uint32_t am = 0xFFFFFFFFu;
  uint32_t bk1 = 0xFFFFFFFFu, bk2 = 0xFFFFFFFFu;

#pragma unroll 4
  for (int g = s + seg; g < e; g += SPLIT) {
    float4 gb = sBox[g];
    float ga = sA[g];
    uint32_t gu = (uint32_t)g;
    {
      uint32_t p = packKey(ax0, ay0, ax1p, ay1p, areaa, gb, ga, gu);
      uint32_t hi = max(p, an1);
      an1 = min(an1, p);
      an2 = min(an2, hi);
    }
    {
      uint32_t p = packKey(b0x0, b0y0, b0x1p, b0y1p, area0, gb, ga, gu);
      am = min(am, p);
    }
    {
      uint32_t p = packKey(b1x0, b1y0, b1x1p, b1y1p, area1, gb, ga, gu);
      uint32_t hi = max(p, bk1);
      bk1 = min(bk1, p);
      bk2 = min(bk2, hi);
    }
  }

#pragma unroll
  for (int m = 1; m <= 2; m <<= 1) {
    uint32_t o1 = (uint32_t)__shfl_xor((int)an1, m, 64);
    uint32_t o2 = (uint32_t)__shfl_xor((int)an2, m, 64);
    uint32_t hi = max(an1, o1);
    an1 = min(an1, o1);
    an2 = min(min(an2, o2), hi);

    am = min(am, (uint32_t)__shfl_xor((int)am, m, 64));

    uint32_t q1 = (uint32_t)__shfl_xor((int)bk1, m, 64);
    uint32_t q2 = (uint32_t)__shfl_xor((int)bk2, m, 64);
    uint32_t hib = max(bk1, q1);
    bk1 = min(bk1, q1);
    bk2 = min(min(bk2, q2), hib);
  }

  if (seg == 0 && pos < A) {
    int i0 = (int)(an1 & 0x1FFu);
    int i1 = (int)(an2 & 0x1FFu);
    int ai = (int)(am & 0x1FFu);
    int bi = (int)(bk1 & 0x1FFu);
    int bi2 = (int)(bk2 & 0x1FFu);

    float4 g0 = sBox[i0]; float a0 = sA[i0]; bool val0 = a0 < 1e29f;
    float v0 = val0 ? iouExact(ax0, ay0, ax1, ay1, areaa, g0, a0) : -1.0f;
    float4 g1 = sBox[i1]; float a1 = sA[i1]; bool val1 = a1 < 1e29f;
    float v1 = val1 ? iouExact(ax0, ay0, ax1, ay1, areaa, g1, a1) : -1.0f;
    float4 ga4 = sBox[ai]; float aav = sA[ai];
    float aval = (aav < 1e29f) ? iouExact(b0x0, b0y0, b0x1, b0y1, area0, ga4, aav) : 0.0f;
    int bIdx = (ai == bi) ? bi2 : bi;
    float4 gb4 = sBox[bIdx]; float abv = sA[bIdx];
    float bval = (abv < 1e29f) ? iouExact(b1x0, b1y0, b1x1, b1y1, area1, gb4, abv) : 0.0f;

    float la = (v0 >= 0.5f) ? 1.0f : ((v0 < 0.4f) ? 0.0f : -1.0f);
    float lbv = (v1 >= 0.5f) ? 1.0f : ((v1 < 0.4f) ? 0.0f : -1.0f);
    float lab0 = la;
    float lab1 = lbv - (((la == 0.0f) && (lbv != 0.0f)) ? 1.0f : 0.0f);

    {
      float p = pcv0;
      if (lab0 != -1.0f) {
        float l = (lab0 == 1.0f) ? 0.25f * (1.0f - p) * (1.0f - p) * logf(p)
                                 : 0.75f * p * p * logf(1.0f - p);
        t_cls -= l;
      }
      if (lab0 > 0.f) t_npos += 1.f;
      float q = pcv1;
      if (lab1 != -1.0f) {
        float l = (lab1 == 1.0f) ? 0.25f * (1.0f - q) * (1.0f - q) * logf(q)
                                 : 0.75f * q * q * logf(1.0f - q);
        t_cls -= l;
      }
      if (lab1 > 0.f) t_npos += 1.f;
    }

    bool fg0 = (lab0 != 0.0f) && (lab0 != -1.0f);
    bool fg1 = (lab1 != 0.0f) && (lab1 != -1.0f);

    float raw = __builtin_amdgcn_rcpf(aw), rah = __builtin_amdgcn_rcpf(ah);

    if (fg0) {
      float mx1 = g0.z - 1.0f, my1 = g0.w - 1.0f;
      float gw = mx1 - g0.x + 1.0f, gh = my1 - g0.y + 1.0f;
      float gcx = g0.x + 0.5f * gw, gcy = g0.y + 0.5f * gh;
      float t0 = (gcx - acx) * raw, t1v = (gcy - acy) * rah;
      float t2 = logf(gw * raw), t3 = logf(gh * rah);
      t_bbox += huber9(d0 - t0) + huber9(d1 - t1v) + huber9(d2 - t2) + huber9(d3 - t3);
      t_nfg += 1.f;
    }
    if (fg1) {
      float mx1 = g1.z - 1.0f, my1 = g1.w - 1.0f;
      float gw = mx1 - g1.x + 1.0f, gh = my1 - g1.y + 1.0f;
      float gcx = g1.x + 0.5f * gw, gcy = g1.y + 0.5f * gh;
      float t0 = (gcx - acx) * raw, t1v = (gcy - acy) * rah;
      float t2 = logf(gw * raw), t3 = logf(gh * rah);
      t_bbox += huber9(d4 - t0) + huber9(d5 - t1v) + huber9(d6 - t2) + huber9(d7 - t3);
      t_nfg += 1.f;
    }

    if (fg0) t_iou += fabsf(riv0 - aval);
    if (fg1) t_iou += fabsf(riv1 - fmaxf(bval, 0.0f));

    {
      int nl = ((lab0 > 0.f) ? 1 : 0) + ((lab1 > 0.f) ? 1 : 0) - 1;
      if (nl != -1) {
        float m = fmaxf(sn0, sn1);
        float lse = m + logf(expf(sn0 - m) + expf(sn1 - m));
        float picked = ((nl == 0) ? sn0 : sn1) - lse;
        t_num -= picked;
        t_ncnt += 1.f;
      }
    }
  }

  float vals[7] = {t_cls, t_bbox, t_iou, t_num, t_npos, t_nfg, t_ncnt};
  int lane = threadIdx.x & 63;
  int wid = threadIdx.x >> 6;
#pragma unroll
  for (int k = 0; k < 7; ++k) {
    float sv = waveSum(vals[k]);
    if (lane == 0) sRed[wid][k] = sv;
  }
  __syncthreads();
  if (threadIdx.x < 7) {
    double sv = (double)sRed[0][threadIdx.x] + (double)sRed[1][threadIdx.x] +
                (double)sRed[2][threadIdx.x] + (double)sRed[3][threadIdx.x];
    atomicAdd(&acc[threadIdx.x * 16], sv);
    __threadfence();
  }
  __syncthreads();
  if (threadIdx.x == 0) {
    unsigned int old = atomicAdd(cnt, 1u);
    sLast = (old == (unsigned int)(totalBlocks - 1)) ? 1 : 0;
  }
  __syncthreads();

  if (sLast && threadIdx.x == 0) {
    __threadfence();
    double cls = atomicAdd(&acc[0 * 16], 0.0);
    double bbox = atomicAdd(&acc[1 * 16], 0.0);
    double iou = atomicAdd(&acc[2 * 16], 0.0);
    double num = atomicAdd(&acc[3 * 16], 0.0);
    double npos = atomicAdd(&acc[4 * 16], 0.0);
    double nfg = atomicAdd(&acc[5 * 16], 0.0);
    double ncnt = atomicAdd(&acc[6 * 16], 0.0);
    double dpos = npos > 1.0 ? npos : 1.0;
    double dfg = nfg > 1.0 ? nfg : 1.0;
    double dcnt = ncnt > 1.0 ? ncnt : 1.0;
    out[0] = (float)(cls / dpos);
    out[1] = (float)(2.0 * bbox / dfg);
    out[2] = (float)(2.0 * iou / dfg);
    out[3] = (float)(num / dcnt);
  }
}

extern "C" void kernel_launch(void* const* d_in, const int* in_sizes, int n_in,
                              void* d_out, int out_size, void* d_ws, size_t ws_size,
                              hipStream_t stream) {
  const float* pred_cls = (const float*)d_in[0];
  const float* rpn_num  = (const float*)d_in[1];
  const float* pred_reg = (const float*)d_in[2];
  const float* anchors  = (const float*)d_in[3];
  const float* rpn_iou  = (const float*)d_in[4];
  const float* boxes    = (const float*)d_in[5];

  int A = in_sizes[3] / 4;
  int n = in_sizes[0] / (2 * A);
  int G = in_sizes[5] / (5 * n);

  char* ws = (char*)d_ws;
  // fixed region (memset to 0 each call)
  double* acc          = (double*)(ws + 0);          // 7*16 doubles = 896 B
  unsigned int* cnt    = (unsigned int*)(ws + 896);  // main ticket
  unsigned int* tick   = (unsigned int*)(ws + 900);  // hist ticket
  unsigned int* binCnt = (unsigned int*)(ws + 1024);     // NBINS u32
  unsigned int* cursor = (unsigned int*)(ws + 1024 + NBINS * 4);
  size_t off = 1024 + 2 * (size_t)NBINS * 4;             // 33792
  float4* sgt = (float4*)(ws + off); off += (size_t)n * G_MAX * 16;
  float* sga  = (float*)(ws + off);  off += (size_t)n * G_MAX * 4;
  float* maxW = (float*)(ws + off);  off += 64;
  int* perm   = (int*)(ws + off);    off += (size_t)A * 4;
  off = (off + 15) & ~(size_t)15;
  float4* gAnch = (float4*)(ws + off); off += (size_t)A * 16;
  float4* gReg  = (float4*)(ws + off); off += (size_t)n * A * 32;
  float2* gPC   = (float2*)(ws + off); off += (size_t)n * A * 8;
  float2* gRI   = (float2*)(ws + off); off += (size_t)n * A * 8;
  float2* gSN   = (float2*)(ws + off); off += (size_t)n * A * 8;
  int gathered = (ws_size >= off) ? 1 : 0;

  hipMemsetAsync(d_ws, 0, 1024 + NBINS * 4, stream);  // acc + tickets + binCnt

  int tb = (A + 255) / 256;
  k_hist_scan<<<tb, 256, 0, stream>>>(anchors, A, tb, binCnt, cursor, tick);
  k_scatter<<<tb, 256, 0, stream>>>(anchors, A, cursor, perm);
  k_sortgt<<<n, 256, 0, stream>>>(boxes, G, sgt, sga, maxW);
  if (gathered)
    k_gather<<<tb, 256, 0, stream>>>(anchors, pred_reg, pred_cls, rpn_iou, rpn_num,
                                     perm, A, n, gAnch, gReg, gPC, gRI, gSN);

  int nBx = (A + 63) / 64;
  int totalBlocks = nBx * n;
  dim3 grid(nBx, n, 1);
  retina_main<<<grid, dim3(256, 1, 1), 0, stream>>>(
      pred_cls, rpn_num, pred_reg, anchors, rpn_iou,
      sgt, sga, maxW, perm, gAnch, gReg, gPC, gRI, gSN,
      gathered, A, totalBlocks, acc, cnt, (float*)d_out);
}

// Round 10
// 179.092 us; speedup vs baseline: 1.6477x; 1.6477x over previous
//
#include <hip/hip_runtime.h>
#include <math.h>

#define G_MAX 512   // LDS capacity for GT boxes; setup uses G=300
#define SPLIT 4     // threads per anchor (g-loop split)

__device__ __forceinline__ float waveSum(float v) {
#pragma unroll
  for (int o = 32; o > 0; o >>= 1) v += __shfl_down(v, o, 64);
  return v;
}

// smooth-L1 with sigma=3 (s2=9)
__device__ __forceinline__ float huber9(float x) {
  float ax = fabsf(x);
  return (ax < (1.0f / 9.0f)) ? 4.5f * x * x : ax - (0.5f / 9.0f);
}

// Exact IoU in the reference's op order. g = (x0, y0, x1+1, y1+1)
__device__ __forceinline__ float iouExact(float bx0, float by0, float bx1, float by1,
                                          float areab, float4 g, float areag) {
  float gx1 = g.z - 1.0f, gy1 = g.w - 1.0f;  // exact inverse of the staged +1
  float iw = fminf(bx1, gx1) - fmaxf(bx0, g.x) + 1.0f;
  float ih = fminf(by1, gy1) - fmaxf(by0, g.y) + 1.0f;
  float inter = fmaxf(iw, 0.f) * fmaxf(ih, 0.f);
  float uni = areab + areag - inter;
  return inter / fmaxf(uni, 1.0f);
}

// Inverse comparison key: key = (areaB+areaG)*rcp(inter); argmax iou == argmin
// key (uint compare on positive floats). ONE-CLAMP trick: inter = max(iw,0)*ih.
//   ih >= 0: identical to the two-clamp value (positive-overlap keys exact).
//   ih <  0: inter <= -0 -> key negative or -inf -> uint >= 0x80000000 ->
//            ranks below ALL positive keys under min-tracking, i.e. in the
//            zero-overlap class, whose internal order is output-invariant
//            (winners are recomputed exactly with validity masks; all
//            zero-overlap/invalid picks yield label 0 / fg=false / value 0).
// Low 9 bits carry g: min-ties resolve to smallest g (jax stable semantics).
// Never NaN: S>0 finite, S*(+-inf)=+-inf.
__device__ __forceinline__ uint32_t packKey(float x0, float y0, float x1p, float y1p,
                                            float area, float4 gb, float ga,
                                            uint32_t g) {
  float iw = fminf(x1p, gb.z) - fmaxf(x0, gb.x);
  float ih = fminf(y1p, gb.w) - fmaxf(y0, gb.y);
  float inter = fmaxf(iw, 0.f) * ih;
  float key = (area + ga) * __builtin_amdgcn_rcpf(inter);
  return (__float_as_uint(key) & 0xFFFFFE00u) | g;
}

__global__ __launch_bounds__(256) void retina_main(
    const float* __restrict__ pred_cls,   // (n, A, 2)
    const float* __restrict__ rpn_num,    // (n, A, 2)
    const float* __restrict__ pred_reg,   // (n, A, 8)
    const float* __restrict__ anchors,    // (A, 4)
    const float* __restrict__ rpn_iou,    // (n, A, 2)
    const float* __restrict__ boxes,      // (n, G, 5)
    int A, int G, int totalBlocks,
    double* __restrict__ acc,             // 7 accumulators, stride 16 doubles
    unsigned int* __restrict__ cnt,       // ticket counter (zeroed)
    float* __restrict__ out)              // 4 floats
{
  __shared__ float4 sBox[G_MAX];  // x0, y0, x1+1, y1+1
  __shared__ float sA[G_MAX];     // area (1e30 for invalid/dummy)
  __shared__ float sRed[4][7];
  __shared__ int sLast;

  const int img = blockIdx.y;
  const int seg = threadIdx.x & (SPLIT - 1);
  const int al  = threadIdx.x >> 2;          // anchor-local 0..63
  const int i   = blockIdx.x * 64 + al;
  const int ic  = (i < A) ? i : (A - 1);

  const int len  = (G + SPLIT - 1) / SPLIT;
  const int padG = len * SPLIT;              // <= G_MAX

  // stage GT boxes (pad range with inert dummies: area=1e30)
  const float* gtb = boxes + (size_t)img * G * 5;
  for (int g = threadIdx.x; g < padG; g += 256) {
    if (g < G) {
      float x0 = gtb[g * 5 + 0], y0 = gtb[g * 5 + 1];
      float x1 = gtb[g * 5 + 2], y1 = gtb[g * 5 + 3];
      float lb = gtb[g * 5 + 4];
      sBox[g] = make_float4(x0, y0, x1 + 1.0f, y1 + 1.0f);
      sA[g] = (lb != -1.0f) ? (x1 - x0 + 1.0f) * (y1 - y0 + 1.0f) : 1e30f;
    } else {
      sBox[g] = make_float4(0.f, 0.f, 1.f, 1.f);
      sA[g] = 1e30f;
    }
  }
  __syncthreads();

  float t_cls = 0.f, t_bbox = 0.f, t_iou = 0.f, t_num = 0.f;
  float t_npos = 0.f, t_nfg = 0.f, t_ncnt = 0.f;

  const float BBOX_CLIP = 4.1351666f;  // log(1000/16)

  // per-anchor data (4 lanes share one anchor; redundant loads hit L1)
  float ax0 = anchors[ic * 4 + 0], ay0 = anchors[ic * 4 + 1];
  float ax1 = anchors[ic * 4 + 2], ay1 = anchors[ic * 4 + 3];
  float aw = ax1 - ax0 + 1.0f, ah = ay1 - ay0 + 1.0f;
  float areaa = aw * ah;
  float acx = ax0 + 0.5f * aw, acy = ay0 + 0.5f * ah;
  float ax1p = ax1 + 1.0f, ay1p = ay1 + 1.0f;

  const float* dp = pred_reg + ((size_t)img * A + ic) * 8;
  float d0 = dp[0], d1 = dp[1], d2 = dp[2], d3 = dp[3];
  float d4 = dp[4], d5 = dp[5], d6 = dp[6], d7 = dp[7];

  // epilogue-only inputs: issue early (exec-masked to seg 0) to hide latency
  float pcv0 = 0.f, pcv1 = 0.f, riv0 = 0.f, riv1 = 0.f, sn0 = 0.f, sn1 = 0.f;
  if (seg == 0) {
    const float* pc = pred_cls + ((size_t)img * A + ic) * 2;
    pcv0 = pc[0]; pcv1 = pc[1];
    const float* ri = rpn_iou + ((size_t)img * A + ic) * 2;
    riv0 = ri[0]; riv1 = ri[1];
    const float* sp = rpn_num + ((size_t)img * A + ic) * 2;
    sn0 = sp[0]; sn1 = sp[1];
  }

  // decode predicted boxes
  float p0cx = acx + d0 * aw, p0cy = acy + d1 * ah;
  float p0w = aw * expf(fminf(d2, BBOX_CLIP));
  float p0h = ah * expf(fminf(d3, BBOX_CLIP));
  float b0x0 = p0cx - 0.5f * p0w, b0y0 = p0cy - 0.5f * p0h;
  float b0x1 = p0cx + 0.5f * p0w, b0y1 = p0cy + 0.5f * p0h;
  float area0 = (b0x1 - b0x0 + 1.0f) * (b0y1 - b0y0 + 1.0f);
  float b0x1p = b0x1 + 1.0f, b0y1p = b0y1 + 1.0f;

  float p1cx = acx + d4 * aw, p1cy = acy + d5 * ah;
  float p1w = aw * expf(fminf(d6, BBOX_CLIP));
  float p1h = ah * expf(fminf(d7, BBOX_CLIP));
  float b1x0 = p1cx - 0.5f * p1w, b1y0 = p1cy - 0.5f * p1h;
  float b1x1 = p1cx + 0.5f * p1w, b1y1 = p1cy + 0.5f * p1h;
  float area1 = (b1x1 - b1x0 + 1.0f) * (b1y1 - b1y0 + 1.0f);
  float b1x1p = b1x1 + 1.0f, b1y1p = b1y1 + 1.0f;

  // min-trackers over inverse keys (merge-associative)
  uint32_t an1 = 0xFFFFFFFFu, an2 = 0xFFFFFFFFu;   // anchor-vs-gt best/2nd
  uint32_t am  = 0xFFFFFFFFu;                      // decoded box 0 best
  uint32_t bk1 = 0xFFFFFFFFu, bk2 = 0xFFFFFFFFu;   // decoded box 1 best/2nd

  int g = seg * len;
#pragma unroll 15
  for (int t = 0; t < len; ++t, ++g) {
    float4 gb = sBox[g];
    float ga = sA[g];
    uint32_t gu = (uint32_t)g;
    {
      uint32_t p = packKey(ax0, ay0, ax1p, ay1p, areaa, gb, ga, gu);
      uint32_t hi = max(p, an1);
      an1 = min(an1, p);
      an2 = min(an2, hi);
    }
    {
      uint32_t p = packKey(b0x0, b0y0, b0x1p, b0y1p, area0, gb, ga, gu);
      am = min(am, p);
    }
    {
      uint32_t p = packKey(b1x0, b1y0, b1x1p, b1y1p, area1, gb, ga, gu);
      uint32_t hi = max(p, bk1);
      bk1 = min(bk1, p);
      bk2 = min(bk2, hi);
    }
  }

  // butterfly merge across the 4 lanes of this anchor
#pragma unroll
  for (int m = 1; m <= 2; m <<= 1) {
    uint32_t o1 = (uint32_t)__shfl_xor((int)an1, m, 64);
    uint32_t o2 = (uint32_t)__shfl_xor((int)an2, m, 64);
    uint32_t hi = max(an1, o1);
    an1 = min(an1, o1);
    an2 = min(min(an2, o2), hi);

    am = min(am, (uint32_t)__shfl_xor((int)am, m, 64));

    uint32_t q1 = (uint32_t)__shfl_xor((int)bk1, m, 64);
    uint32_t q2 = (uint32_t)__shfl_xor((int)bk2, m, 64);
    uint32_t hib = max(bk1, q1);
    bk1 = min(bk1, q1);
    bk2 = min(min(bk2, q2), hib);
  }

  if (seg == 0 && i < A) {
    // winning indices; clamp defensively to the initialized LDS range
    int pg1 = padG - 1;
    int i0 = min((int)(an1 & 0x1FFu), pg1);
    int i1 = min((int)(an2 & 0x1FFu), pg1);
    int ai = min((int)(am  & 0x1FFu), pg1);
    int bi = min((int)(bk1 & 0x1FFu), pg1);
    int bi2= min((int)(bk2 & 0x1FFu), pg1);

    // exact recompute of winning values (reference op order, explicit validity)
    float4 g0 = sBox[i0]; float a0 = sA[i0]; bool val0 = a0 < 1e29f;
    float v0 = val0 ? iouExact(ax0, ay0, ax1, ay1, areaa, g0, a0) : -1.0f;
    float4 g1 = sBox[i1]; float a1 = sA[i1]; bool val1 = a1 < 1e29f;
    float v1 = val1 ? iouExact(ax0, ay0, ax1, ay1, areaa, g1, a1) : -1.0f;
    float4 ga4 = sBox[ai]; float aav = sA[ai];
    float aval = (aav < 1e29f) ? iouExact(b0x0, b0y0, b0x1, b0y1, area0, ga4, aav) : 0.0f;
    int bIdx = (ai == bi) ? bi2 : bi;  // b with b[ai] zeroed, then argmax
    float4 gb4 = sBox[bIdx]; float abv = sA[bIdx];
    float bval = (abv < 1e29f) ? iouExact(b1x0, b1y0, b1x1, b1y1, area1, gb4, abv) : 0.0f;

    // labels: >=0.5 -> 1, <0.4 -> 0, else -1
    float la  = (v0 >= 0.5f) ? 1.0f : ((v0 < 0.4f) ? 0.0f : -1.0f);
    float lbv = (v1 >= 0.5f) ? 1.0f : ((v1 < 0.4f) ? 0.0f : -1.0f);
    float lab0 = la;
    float lab1 = lbv - (((la == 0.0f) && (lbv != 0.0f)) ? 1.0f : 0.0f);

    // ---- focal classification loss ----
    {
      float p = pcv0;
      if (lab0 != -1.0f) {
        float l = (lab0 == 1.0f)
                      ? 0.25f * (1.0f - p) * (1.0f - p) * logf(p)
                      : 0.75f * p * p * logf(1.0f - p);
        t_cls -= l;
      }
      if (lab0 > 0.f) t_npos += 1.f;
      float q = pcv1;
      if (lab1 != -1.0f) {
        float l = (lab1 == 1.0f)
                      ? 0.25f * (1.0f - q) * (1.0f - q) * logf(q)
                      : 0.75f * q * q * logf(1.0f - q);
        t_cls -= l;
      }
      if (lab1 > 0.f) t_npos += 1.f;
    }

    bool fg0 = (lab0 != 0.0f) && (lab0 != -1.0f);
    bool fg1 = (lab1 != 0.0f) && (lab1 != -1.0f);

    // fast reciprocals for the bbox-target divides (rel err ~1e-7, harmless)
    float raw = __builtin_amdgcn_rcpf(aw), rah = __builtin_amdgcn_rcpf(ah);

    // ---- bbox smooth-L1 vs bbox_transform(anchor, matched gt) ----
    if (fg0) {
      float mx1 = g0.z - 1.0f, my1 = g0.w - 1.0f;
      float gw = mx1 - g0.x + 1.0f, gh = my1 - g0.y + 1.0f;
      float gcx = g0.x + 0.5f * gw, gcy = g0.y + 0.5f * gh;
      float t0 = (gcx - acx) * raw, t1v = (gcy - acy) * rah;
      float t2 = logf(gw * raw), t3 = logf(gh * rah);
      t_bbox += huber9(d0 - t0) + huber9(d1 - t1v) + huber9(d2 - t2) + huber9(d3 - t3);
      t_nfg += 1.f;
    }
    if (fg1) {
      float mx1 = g1.z - 1.0f, my1 = g1.w - 1.0f;
      float gw = mx1 - g1.x + 1.0f, gh = my1 - g1.y + 1.0f;
      float gcx = g1.x + 0.5f * gw, gcy = g1.y + 0.5f * gh;
      float t0 = (gcx - acx) * raw, t1v = (gcy - acy) * rah;
      float t2 = logf(gw * raw), t3 = logf(gh * rah);
      t_bbox += huber9(d4 - t0) + huber9(d5 - t1v) + huber9(d6 - t2) + huber9(d7 - t3);
      t_nfg += 1.f;
    }

    // ---- IoU L1 loss ----
    if (fg0) t_iou += fabsf(riv0 - aval);
    if (fg1) t_iou += fabsf(riv1 - fmaxf(bval, 0.0f));

    // ---- num softmax loss ----
    {
      int nl = ((lab0 > 0.f) ? 1 : 0) + ((lab1 > 0.f) ? 1 : 0) - 1;
      if (nl != -1) {
        float m = fmaxf(sn0, sn1);
        float lse = m + logf(expf(sn0 - m) + expf(sn1 - m));
        float picked = ((nl == 0) ? sn0 : sn1) - lse;
        t_num -= picked;
        t_ncnt += 1.f;
      }
    }
  }

  // block reduction: wave shuffle -> LDS -> one double atomic per scalar
  float vals[7] = {t_cls, t_bbox, t_iou, t_num, t_npos, t_nfg, t_ncnt};
  int lane = threadIdx.x & 63;
  int wid = threadIdx.x >> 6;
#pragma unroll
  for (int k = 0; k < 7; ++k) {
    float s = waveSum(vals[k]);
    if (lane == 0) sRed[wid][k] = s;
  }
  __syncthreads();
  if (threadIdx.x < 7) {
    double s = (double)sRed[0][threadIdx.x] + (double)sRed[1][threadIdx.x] +
               (double)sRed[2][threadIdx.x] + (double)sRed[3][threadIdx.x];
    atomicAdd(&acc[threadIdx.x * 16], s);  // 128 B apart, device-scope
    __threadfence();                       // release our adds device-wide
  }
  __syncthreads();
  if (threadIdx.x == 0) {
    unsigned int old = atomicAdd(cnt, 1u); // ticket; device-scope
    sLast = (old == (unsigned int)(totalBlocks - 1)) ? 1 : 0;
  }
  __syncthreads();

  // last block finalizes: read accumulators through the atomic domain
  if (sLast && threadIdx.x == 0) {
    __threadfence();
    double cls  = atomicAdd(&acc[0 * 16], 0.0);
    double bbox = atomicAdd(&acc[1 * 16], 0.0);
    double iou  = atomicAdd(&acc[2 * 16], 0.0);
    double num  = atomicAdd(&acc[3 * 16], 0.0);
    double npos = atomicAdd(&acc[4 * 16], 0.0);
    double nfg  = atomicAdd(&acc[5 * 16], 0.0);
    double ncnt = atomicAdd(&acc[6 * 16], 0.0);
    double dpos = npos > 1.0 ? npos : 1.0;
    double dfg  = nfg  > 1.0 ? nfg  : 1.0;
    double dcnt = ncnt > 1.0 ? ncnt : 1.0;
    out[0] = (float)(cls / dpos);
    out[1] = (float)(2.0 * bbox / dfg);
    out[2] = (float)(2.0 * iou / dfg);
    out[3] = (float)(num / dcnt);
  }
}

extern "C" void kernel_launch(void* const* d_in, const int* in_sizes, int n_in,
                              void* d_out, int out_size, void* d_ws, size_t ws_size,
                              hipStream_t stream) {
  const float* pred_cls = (const float*)d_in[0];
  const float* rpn_num  = (const float*)d_in[1];
  const float* pred_reg = (const float*)d_in[2];
  const float* anchors  = (const float*)d_in[3];
  const float* rpn_iou  = (const float*)d_in[4];
  const float* boxes    = (const float*)d_in[5];
  // d_in[6] = im_info: unused by the reference math

  int A = in_sizes[3] / 4;
  int n = in_sizes[0] / (2 * A);
  int G = in_sizes[5] / (5 * n);

  double* acc = (double*)d_ws;                       // 7 x stride-16 doubles
  unsigned int* cnt = (unsigned int*)((char*)d_ws + 7 * 16 * sizeof(double));
  hipMemsetAsync(d_ws, 0, 7 * 16 * sizeof(double) + sizeof(unsigned int), stream);

  int nBx = (A + 63) / 64;
  int totalBlocks = nBx * n;
  dim3 grid(nBx, n, 1);  // 64 anchors/block x SPLIT=4 lanes
  retina_main<<<grid, dim3(256, 1, 1), 0, stream>>>(
      pred_cls, rpn_num, pred_reg, anchors, rpn_iou, boxes,
      A, G, totalBlocks, acc, cnt, (float*)d_out);
}